// Round 20
// baseline (220.345 us; speedup 1.0000x reference)
//
#include <hip/hip_runtime.h>

#define NIN 64
#define NOUT 32
#define KK 9
#define TT 4     // output tiles (of 16 rows) per wave in the gather
#define IST 12   // inv_t row stride (9 used, pad to 12 for 16B alignment)

typedef __attribute__((ext_vector_type(8))) short bf16x8;
typedef __attribute__((ext_vector_type(4))) float f32x4;
typedef __attribute__((ext_vector_type(16))) float f32x16;
typedef __attribute__((ext_vector_type(8))) unsigned short u16x8;

// fp32 -> bf16 round-to-nearest-even
__device__ __forceinline__ unsigned short f2bf_rne(float f) {
    unsigned int u = __builtin_bit_cast(unsigned int, f);
    unsigned int r = (u + 0x7FFFu + ((u >> 16) & 1u)) >> 16;
    return (unsigned short)r;
}
__device__ __forceinline__ float bf2f(unsigned short h) {
    unsigned int u = ((unsigned int)h) << 16;
    return __builtin_bit_cast(float, u);
}

// ---------------------------------------------------------------------------
// Setup: fused prep_w16 + inv_t fill + repmin fill.
__global__ void mink_setup(const float* __restrict__ w,
                           unsigned short* __restrict__ wfB,
                           int4* __restrict__ invt4, long long invt4c,
                           int4* __restrict__ rep4, long long rep4c) {
    long long tid = (long long)blockIdx.x * 256 + threadIdx.x;
    if (tid < 36 * 64) {
        int t = (int)tid;
        int lane = t & 63, fid = t >> 6;
        int ch = fid & 1, kh = (fid >> 1) & 1, k = fid >> 2;
        int g = lane >> 4, col = ch * 16 + (lane & 15);
        #pragma unroll
        for (int j = 0; j < 8; ++j) {
            int ci = kh * 32 + 16 * (j >> 2) + g * 4 + (j & 3);
            wfB[(size_t)fid * 512 + lane * 8 + j] =
                f2bf_rne(w[(k * NIN + ci) * NOUT + col]);
        }
    }
    long long stride = (long long)gridDim.x * 256;
    int4 neg1 = {-1, -1, -1, -1};
    int4 imax = {0x7FFFFFFF, 0x7FFFFFFF, 0x7FFFFFFF, 0x7FFFFFFF};
    for (long long i = tid; i < invt4c; i += stride) invt4[i] = neg1;
    for (long long i = tid; i < rep4c; i += stride) rep4[i] = imax;
}

// ---------------------------------------------------------------------------
// Step 1: representative site per cell = min site id sharing the center row.
__global__ void mink_rep(const int* __restrict__ oidx, int* __restrict__ repmin,
                         int n) {
    int i = blockIdx.x * 256 + threadIdx.x;
    if (i < n) atomicMin(&repmin[oidx[(size_t)i * KK + 4]], i);
}

// ---------------------------------------------------------------------------
// Step 1b: PER-THREAD resolve (64 independent miss chains per wave).
__global__ void mink_resolve(const int* __restrict__ oidx,
                             const int* __restrict__ repmin,
                             int* __restrict__ rep_of, int n) {
    int i = blockIdx.x * 256 + threadIdx.x;
    if (i < n) rep_of[i] = repmin[oidx[(size_t)i * KK + 4]];
}

// ---------------------------------------------------------------------------
// Step 2a: float4 copy (domain A, round 20: 16 B/lane per G13) + inv_t build
// (domain B, transposed [num_out][12] rows). MUST stay a separate launch
// from dup_accum (round-10: plain stores precede atomics).
__global__ void mink_copy_inv(
    const float4* __restrict__ feats4, const int* __restrict__ oidx,
    const int* __restrict__ repmin, const int* __restrict__ rep_of,
    float4* __restrict__ buf4, int* __restrict__ inv_t, int n, int num_out) {
    long long t = (long long)blockIdx.x * 256 + threadIdx.x;
    long long nA = (long long)n * (NIN / 4);
    if (t < nA) {
        int site = (int)(t >> 4);
        if (rep_of[site] == site) buf4[t] = feats4[t];
    } else {
        int r = (int)(t - nA);
        if (r < num_out) {
            int rep = repmin[r];
            if (rep != 0x7FFFFFFF) {
                const int* ip = oidx + (size_t)rep * KK;
                #pragma unroll
                for (int k = 0; k < KK; ++k) {
                    int row = (k == 4) ? r : ip[k];
                    inv_t[(size_t)row * IST + k] = rep;
                }
            }
        }
    }
}

// ---------------------------------------------------------------------------
// Step 2b: duplicates add into buf[rep]; float4 feats load feeds 4 dword
// atomics (round 20 vectorization); line-touch count unchanged.
__global__ void mink_dup_accum(const float4* __restrict__ feats4,
                               const int* __restrict__ rep_of,
                               float* __restrict__ buf, int n) {
    int t = blockIdx.x * 256 + threadIdx.x;
    int site = t >> 4;
    if (site >= n) return;
    int rep = rep_of[site];
    if (rep != site) {
        float4 v = feats4[t];
        float* dst = buf + (size_t)rep * NIN + (t & 15) * 4;
        unsafeAtomicAdd(dst + 0, v.x);
        unsafeAtomicAdd(dst + 1, v.y);
        unsafeAtomicAdd(dst + 2, v.z);
        unsafeAtomicAdd(dst + 3, v.w);
    }
}

// ---------------------------------------------------------------------------
// Step 3: pack summed fp32 row -> single-bf16 A fragments, in place.
__global__ void mink_pack16(const int* __restrict__ rep_of,
                            float* __restrict__ buf, int n) {
    int i = blockIdx.x * 256 + threadIdx.x;
    if (i >= n) return;
    if (rep_of[i] != i) return;

    float x[NIN];
    float4* p4 = (float4*)(buf + (size_t)i * NIN);
    #pragma unroll
    for (int j = 0; j < NIN / 4; ++j) {
        float4 v = p4[j];
        x[j * 4 + 0] = v.x; x[j * 4 + 1] = v.y;
        x[j * 4 + 2] = v.z; x[j * 4 + 3] = v.w;
    }
    #pragma unroll
    for (int kh = 0; kh < 2; ++kh) {
        #pragma unroll
        for (int g = 0; g < 4; ++g) {
            u16x8 a;
            #pragma unroll
            for (int j = 0; j < 8; ++j) {
                int c = kh * 32 + 16 * (j >> 2) + g * 4 + (j & 3);
                a[j] = f2bf_rne(x[c]);
            }
            p4[kh * 4 + g] = __builtin_bit_cast(float4, a);
        }
    }
}

// ---------------------------------------------------------------------------
// Step 5: 16x16x32 gather. Round 20: inv_t transposed -> per tile-row all 9
// k-indices load as 3 dwordx4 (inv VMEM instrs 40->12 per wave; VGPR growth
// harmless per R18's occupancy-flat finding). B in LDS (R19), XCD swizzle,
// adjacent row-half stores.
__global__ __launch_bounds__(256) void mink_gather16(
    const float* __restrict__ buf,          // packed bf16 A rows (128 B used)
    const unsigned short* __restrict__ wfB, // 36 frags x 1 KB
    const int* __restrict__ inv_t,          // [num_out][12]
    const float* __restrict__ bias,         // [32]
    float* __restrict__ out,                // [num_out, 32]
    int num_out) {
    __shared__ unsigned short wlds[36 * 512];   // 36 KB
    {
        const int4* src = (const int4*)wfB;
        int4* dst = (int4*)wlds;
        #pragma unroll
        for (int i = 0; i < 9; ++i) {
            dst[threadIdx.x + i * 256] = src[threadIdx.x + i * 256];
        }
    }
    __syncthreads();

    // bijective XCD chunk swizzle (m204)
    int nblk = gridDim.x;
    int b = blockIdx.x;
    int q = nblk >> 3, r8 = nblk & 7;
    int xcd = b & 7, pos = b >> 3;
    int swz = (xcd < r8 ? xcd * (q + 1) : r8 * (q + 1) + (xcd - r8) * q) + pos;

    int wid  = swz * 4 + (threadIdx.x >> 6);
    int lane = threadIdx.x & 63;
    int r0   = wid * (16 * TT);
    if (r0 >= num_out) return;
    int g   = lane >> 4;
    int c16 = lane & 15;

    // all 9*TT inv indices via 3 dwordx4 per tile-row
    int iv[KK][TT];
    #pragma unroll
    for (int t = 0; t < TT; ++t) {
        int r = r0 + t * 16 + c16;
        if (r < num_out) {
            const int* rowp = inv_t + (size_t)r * IST;
            int4 ia = *(const int4*)(rowp);
            int4 ib = *(const int4*)(rowp + 4);
            int4 ic = *(const int4*)(rowp + 8);
            iv[0][t] = ia.x; iv[1][t] = ia.y; iv[2][t] = ia.z; iv[3][t] = ia.w;
            iv[4][t] = ib.x; iv[5][t] = ib.y; iv[6][t] = ib.z; iv[7][t] = ib.w;
            iv[8][t] = ic.x;
        } else {
            #pragma unroll
            for (int k = 0; k < KK; ++k) iv[k][t] = -1;
        }
    }

    f32x4 acc[TT][2];
    #pragma unroll
    for (int t = 0; t < TT; ++t) {
        acc[t][0] = (f32x4){0, 0, 0, 0};
        acc[t][1] = (f32x4){0, 0, 0, 0};
    }

    #pragma unroll
    for (int k = 0; k < KK; ++k) {
        bf16x8 a0[TT], a1[TT];
        #pragma unroll
        for (int t = 0; t < TT; ++t) {
            a0[t] = (bf16x8){0,0,0,0,0,0,0,0};
            a1[t] = (bf16x8){0,0,0,0,0,0,0,0};
            if (iv[k][t] >= 0) {
                const bf16x8* ab = (const bf16x8*)(buf + (size_t)iv[k][t] * NIN);
                a0[t] = ab[g];
                a1[t] = ab[4 + g];
            }
        }
        #pragma unroll
        for (int kh = 0; kh < 2; ++kh) {
            #pragma unroll
            for (int ch = 0; ch < 2; ++ch) {
                bf16x8 bb = *(const bf16x8*)(
                    wlds + (size_t)((k * 2 + kh) * 2 + ch) * 512 + lane * 8);
                #pragma unroll
                for (int t = 0; t < TT; ++t) {
                    bf16x8 a = kh ? a1[t] : a0[t];
                    acc[t][ch] = __builtin_amdgcn_mfma_f32_16x16x32_bf16(
                        a, bb, acc[t][ch], 0, 0, 0);
                }
            }
        }
    }

    // C/D: row = g*4 + reg, col = ch*16 + c16; ch innermost (adjacent halves).
    float bb0 = bias[c16];
    float bb1 = bias[16 + c16];
    #pragma unroll
    for (int t = 0; t < TT; ++t) {
        #pragma unroll
        for (int reg = 0; reg < 4; ++reg) {
            int orow = r0 + t * 16 + g * 4 + reg;
            if (orow < num_out) {
                out[(size_t)orow * NOUT + c16]      = fmaxf(acc[t][0][reg] + bb0, 0.0f);
                out[(size_t)orow * NOUT + 16 + c16] = fmaxf(acc[t][1][reg] + bb1, 0.0f);
            }
        }
    }
}

// ---------------------------------------------------------------------------
// Fallback path (round-4 atomic scatter) if d_ws is too small.
__global__ void mink_prep_w32(const float* __restrict__ w,
                              unsigned short* __restrict__ wf) {
    int t = blockIdx.x * 256 + threadIdx.x;
    if (t >= KK * 4 * 64) return;
    int l = t & 63, ks = (t >> 6) & 3, k = t >> 8;
    int col = l & 31;
    int kb = ks * 16 + (l >> 5) * 4;
    #pragma unroll
    for (int j = 0; j < 8; ++j) {
        int c = kb + (j & 3) + 8 * (j >> 2);
        float v = w[(k * NIN + c) * NOUT + col];
        unsigned short hi = f2bf_rne(v);
        unsigned short lo = f2bf_rne(v - bf2f(hi));
        wf[(size_t)((k * 4 + ks) * 64 + l) * 8 + j] = hi;
        wf[(size_t)(KK * 4 * 64 * 8) + (size_t)((k * 4 + ks) * 64 + l) * 8 + j] = lo;
    }
}

__global__ void mink_init_bias(float4* __restrict__ out,
                               const float4* __restrict__ bias, int n4) {
    int i = blockIdx.x * blockDim.x + threadIdx.x;
    if (i < n4) out[i] = bias[i & 7];
}

__global__ __launch_bounds__(256) void mink_scatter_mfma(
    const float* __restrict__ feats,
    const unsigned short* __restrict__ wf,
    const int* __restrict__ out_idx,
    float* __restrict__ out,
    int ntiles) {
    int wid  = (blockIdx.x * 256 + threadIdx.x) >> 6;
    int lane = threadIdx.x & 63;
    if (wid >= ntiles) return;
    int n0   = wid * 32;
    int half = lane >> 5;
    int col  = lane & 31;

    const float* xrow = feats + (size_t)(n0 + col) * NIN;
    int kbase = half * 4;
    bf16x8 ahi[4], alo[4];
    #pragma unroll
    for (int ks = 0; ks < 4; ++ks) {
        float4 v0 = *(const float4*)(xrow + ks * 16 + kbase);
        float4 v1 = *(const float4*)(xrow + ks * 16 + kbase + 8);
        float xs[8] = {v0.x, v0.y, v0.z, v0.w, v1.x, v1.y, v1.z, v1.w};
        #pragma unroll
        for (int j = 0; j < 8; ++j) {
            unsigned short h = f2bf_rne(xs[j]);
            ahi[ks][j] = (short)h;
            alo[ks][j] = (short)f2bf_rne(xs[j] - bf2f(h));
        }
    }
    const bf16x8* wfh = (const bf16x8*)wf;
    const bf16x8* wfl = wfh + KK * 4 * 64;
    #pragma unroll 1
    for (int k = 0; k < KK; ++k) {
        f32x16 acc = {0,0,0,0,0,0,0,0,0,0,0,0,0,0,0,0};
        #pragma unroll
        for (int ks = 0; ks < 4; ++ks) {
            bf16x8 bh = wfh[(k * 4 + ks) * 64 + lane];
            bf16x8 bl = wfl[(k * 4 + ks) * 64 + lane];
            acc = __builtin_amdgcn_mfma_f32_32x32x16_bf16(ahi[ks], bh, acc, 0, 0, 0);
            acc = __builtin_amdgcn_mfma_f32_32x32x16_bf16(ahi[ks], bl, acc, 0, 0, 0);
            acc = __builtin_amdgcn_mfma_f32_32x32x16_bf16(alo[ks], bh, acc, 0, 0, 0);
        }
        #pragma unroll
        for (int rr = 0; rr < 16; ++rr) {
            int site = (rr & 3) + 8 * (rr >> 2) + 4 * half;
            int row = out_idx[(size_t)(n0 + site) * KK + k];
            unsafeAtomicAdd(out + (size_t)row * NOUT + col, acc[rr]);
        }
    }
}

__global__ void mink_relu(float4* __restrict__ out, int n4) {
    int i = blockIdx.x * blockDim.x + threadIdx.x;
    if (i < n4) {
        float4 v = out[i];
        v.x = fmaxf(v.x, 0.0f);
        v.y = fmaxf(v.y, 0.0f);
        v.z = fmaxf(v.z, 0.0f);
        v.w = fmaxf(v.w, 0.0f);
        out[i] = v;
    }
}

extern "C" void kernel_launch(void* const* d_in, const int* in_sizes, int n_in,
                              void* d_out, int out_size, void* d_ws, size_t ws_size,
                              hipStream_t stream) {
    const float* feats  = (const float*)d_in[0];  // [N, 64] f32
    const float* weight = (const float*)d_in[1];  // [9, 64, 32] f32
    const float* bias   = (const float*)d_in[2];  // [32] f32
    const int*   oidx   = (const int*)d_in[3];    // [N, 9] i32
    float* out = (float*)d_out;                   // [num_out, 32] f32

    int n       = in_sizes[0] / NIN;              // 262144
    int n4      = out_size / 4;
    int num_out = out_size / NOUT;

    // d_ws layout: wf(73728 reserved) | repmin | rep_of[n] | inv_t | buf
    unsigned short* wf = (unsigned short*)d_ws;
    size_t off = 73728;
    int* repmin = (int*)((char*)d_ws + off);  off += (size_t)num_out * 4 + 16;
    off = (off + 255) & ~(size_t)255;
    int* rep_of = (int*)((char*)d_ws + off);  off += (size_t)n * 4;
    off = (off + 255) & ~(size_t)255;
    int* inv_t  = (int*)((char*)d_ws + off);  off += (size_t)IST * num_out * 4 + 16;
    off = (off + 255) & ~(size_t)255;
    float* buf  = (float*)((char*)d_ws + off); off += (size_t)n * NIN * 4;

    if (off <= ws_size) {
        // ---- inverse-map 16x16 gather path (no output atomics)
        long long invt4c = ((long long)IST * num_out + 3) / 4;
        long long rep4c  = ((long long)num_out + 3) / 4;
        mink_setup<<<2048, 256, 0, stream>>>(
            weight, wf, (int4*)inv_t, invt4c, (int4*)repmin, rep4c);

        mink_rep<<<(n + 255) / 256, 256, 0, stream>>>(oidx, repmin, n);
        mink_resolve<<<(n + 255) / 256, 256, 0, stream>>>(oidx, repmin, rep_of, n);

        long long nthr = (long long)n * (NIN / 4) + num_out;
        mink_copy_inv<<<(int)((nthr + 255) / 256), 256, 0, stream>>>(
            (const float4*)feats, oidx, repmin, rep_of,
            (float4*)buf, inv_t, n, num_out);

        long long dthr = (long long)n * (NIN / 4);
        mink_dup_accum<<<(int)((dthr + 255) / 256), 256, 0, stream>>>(
            (const float4*)feats, rep_of, buf, n);

        mink_pack16<<<(n + 255) / 256, 256, 0, stream>>>(rep_of, buf, n);

        int nwave = (num_out + 16 * TT - 1) / (16 * TT);
        mink_gather16<<<(nwave + 3) / 4, 256, 0, stream>>>(
            buf, wf, inv_t, bias, out, num_out);
    } else {
        // ---- fallback: round-4 atomic scatter
        mink_prep_w32<<<(KK * 4 * 64 + 255) / 256, 256, 0, stream>>>(weight, wf);
        mink_init_bias<<<(n4 + 255) / 256, 256, 0, stream>>>(
            (float4*)out, (const float4*)bias, n4);
        int ntiles = n / 32;
        mink_scatter_mfma<<<ntiles * 64 / 256, 256, 0, stream>>>(
            feats, wf, oidx, out, ntiles);
        mink_relu<<<(n4 + 255) / 256, 256, 0, stream>>>((float4*)out, n4);
    }
}

// Round 21
// 169.111 us; speedup vs baseline: 1.3030x; 1.3030x over previous
//
#include <hip/hip_runtime.h>

#define NIN 64
#define NOUT 32
#define KK 9
#define TT 4     // output tiles (of 16 rows) per wave in the gather
#define IST 12   // inv_t row stride (9 used, pad to 12 for 16B alignment)

typedef __attribute__((ext_vector_type(8))) short bf16x8;
typedef __attribute__((ext_vector_type(4))) float f32x4;
typedef __attribute__((ext_vector_type(16))) float f32x16;
typedef __attribute__((ext_vector_type(8))) unsigned short u16x8;

// fp32 -> bf16 round-to-nearest-even
__device__ __forceinline__ unsigned short f2bf_rne(float f) {
    unsigned int u = __builtin_bit_cast(unsigned int, f);
    unsigned int r = (u + 0x7FFFu + ((u >> 16) & 1u)) >> 16;
    return (unsigned short)r;
}
__device__ __forceinline__ float bf2f(unsigned short h) {
    unsigned int u = ((unsigned int)h) << 16;
    return __builtin_bit_cast(float, u);
}

// ---------------------------------------------------------------------------
// Setup: fused prep_w16 + inv_t fill + repmin fill.
__global__ void mink_setup(const float* __restrict__ w,
                           unsigned short* __restrict__ wfB,
                           int4* __restrict__ invt4, long long invt4c,
                           int4* __restrict__ rep4, long long rep4c) {
    long long tid = (long long)blockIdx.x * 256 + threadIdx.x;
    if (tid < 36 * 64) {
        int t = (int)tid;
        int lane = t & 63, fid = t >> 6;
        int ch = fid & 1, kh = (fid >> 1) & 1, k = fid >> 2;
        int g = lane >> 4, col = ch * 16 + (lane & 15);
        #pragma unroll
        for (int j = 0; j < 8; ++j) {
            int ci = kh * 32 + 16 * (j >> 2) + g * 4 + (j & 3);
            wfB[(size_t)fid * 512 + lane * 8 + j] =
                f2bf_rne(w[(k * NIN + ci) * NOUT + col]);
        }
    }
    long long stride = (long long)gridDim.x * 256;
    int4 neg1 = {-1, -1, -1, -1};
    int4 imax = {0x7FFFFFFF, 0x7FFFFFFF, 0x7FFFFFFF, 0x7FFFFFFF};
    for (long long i = tid; i < invt4c; i += stride) invt4[i] = neg1;
    for (long long i = tid; i < rep4c; i += stride) rep4[i] = imax;
}

// ---------------------------------------------------------------------------
// Step 1: representative site per cell = min site id sharing the center row.
__global__ void mink_rep(const int* __restrict__ oidx, int* __restrict__ repmin,
                         int n) {
    int i = blockIdx.x * 256 + threadIdx.x;
    if (i < n) atomicMin(&repmin[oidx[(size_t)i * KK + 4]], i);
}

// ---------------------------------------------------------------------------
// Step 1b: PER-THREAD resolve (64 independent miss chains per wave).
__global__ void mink_resolve(const int* __restrict__ oidx,
                             const int* __restrict__ repmin,
                             int* __restrict__ rep_of, int n) {
    int i = blockIdx.x * 256 + threadIdx.x;
    if (i < n) rep_of[i] = repmin[oidx[(size_t)i * KK + 4]];
}

// ---------------------------------------------------------------------------
// Step 2a: float4 copy (domain A) + inv_t build (domain B, transposed
// [num_out][12] rows). MUST stay a separate launch from dup_accum
// (round-10: plain stores precede atomics).
__global__ void mink_copy_inv(
    const float4* __restrict__ feats4, const int* __restrict__ oidx,
    const int* __restrict__ repmin, const int* __restrict__ rep_of,
    float4* __restrict__ buf4, int* __restrict__ inv_t, int n, int num_out) {
    long long t = (long long)blockIdx.x * 256 + threadIdx.x;
    long long nA = (long long)n * (NIN / 4);
    if (t < nA) {
        int site = (int)(t >> 4);
        if (rep_of[site] == site) buf4[t] = feats4[t];
    } else {
        int r = (int)(t - nA);
        if (r < num_out) {
            int rep = repmin[r];
            if (rep != 0x7FFFFFFF) {
                const int* ip = oidx + (size_t)rep * KK;
                #pragma unroll
                for (int k = 0; k < KK; ++k) {
                    int row = (k == 4) ? r : ip[k];
                    inv_t[(size_t)row * IST + k] = rep;
                }
            }
        }
    }
}

// ---------------------------------------------------------------------------
// Step 2b: duplicates add into buf[rep]. REVERTED to round-19's wave-per-site
// scalar mapping (thread = site*64 + chan): one atomic instruction covers 64
// CONTIGUOUS dwords of one site's row -> 4 line touches/site. Round 20's
// float4 form (4 sites/wave x 4 sequential atomics at stride-16) touched the
// same lines 4x -> 16 touches/site -> 4x slower at the fixed ~18.5G lines/s
// atomic cap. Atomics coalesce across LANES within one instruction only.
__global__ void mink_dup_accum(const float* __restrict__ feats,
                               const int* __restrict__ rep_of,
                               float* __restrict__ buf, int n) {
    int t = blockIdx.x * 256 + threadIdx.x;
    int site = t >> 6;
    if (site >= n) return;
    int rep = rep_of[site];
    if (rep != site)
        unsafeAtomicAdd(buf + (size_t)rep * NIN + (t & 63), feats[t]);
}

// ---------------------------------------------------------------------------
// Step 3: pack summed fp32 row -> single-bf16 A fragments, in place.
__global__ void mink_pack16(const int* __restrict__ rep_of,
                            float* __restrict__ buf, int n) {
    int i = blockIdx.x * 256 + threadIdx.x;
    if (i >= n) return;
    if (rep_of[i] != i) return;

    float x[NIN];
    float4* p4 = (float4*)(buf + (size_t)i * NIN);
    #pragma unroll
    for (int j = 0; j < NIN / 4; ++j) {
        float4 v = p4[j];
        x[j * 4 + 0] = v.x; x[j * 4 + 1] = v.y;
        x[j * 4 + 2] = v.z; x[j * 4 + 3] = v.w;
    }
    #pragma unroll
    for (int kh = 0; kh < 2; ++kh) {
        #pragma unroll
        for (int g = 0; g < 4; ++g) {
            u16x8 a;
            #pragma unroll
            for (int j = 0; j < 8; ++j) {
                int c = kh * 32 + 16 * (j >> 2) + g * 4 + (j & 3);
                a[j] = f2bf_rne(x[c]);
            }
            p4[kh * 4 + g] = __builtin_bit_cast(float4, a);
        }
    }
}

// ---------------------------------------------------------------------------
// Step 5: 16x16x32 gather. inv_t transposed (3 dwordx4 per tile-row, R20),
// B in LDS (R19), XCD swizzle, adjacent row-half stores.
__global__ __launch_bounds__(256) void mink_gather16(
    const float* __restrict__ buf,          // packed bf16 A rows (128 B used)
    const unsigned short* __restrict__ wfB, // 36 frags x 1 KB
    const int* __restrict__ inv_t,          // [num_out][12]
    const float* __restrict__ bias,         // [32]
    float* __restrict__ out,                // [num_out, 32]
    int num_out) {
    __shared__ unsigned short wlds[36 * 512];   // 36 KB
    {
        const int4* src = (const int4*)wfB;
        int4* dst = (int4*)wlds;
        #pragma unroll
        for (int i = 0; i < 9; ++i) {
            dst[threadIdx.x + i * 256] = src[threadIdx.x + i * 256];
        }
    }
    __syncthreads();

    // bijective XCD chunk swizzle (m204)
    int nblk = gridDim.x;
    int b = blockIdx.x;
    int q = nblk >> 3, r8 = nblk & 7;
    int xcd = b & 7, pos = b >> 3;
    int swz = (xcd < r8 ? xcd * (q + 1) : r8 * (q + 1) + (xcd - r8) * q) + pos;

    int wid  = swz * 4 + (threadIdx.x >> 6);
    int lane = threadIdx.x & 63;
    int r0   = wid * (16 * TT);
    if (r0 >= num_out) return;
    int g   = lane >> 4;
    int c16 = lane & 15;

    // all 9*TT inv indices via 3 dwordx4 per tile-row
    int iv[KK][TT];
    #pragma unroll
    for (int t = 0; t < TT; ++t) {
        int r = r0 + t * 16 + c16;
        if (r < num_out) {
            const int* rowp = inv_t + (size_t)r * IST;
            int4 ia = *(const int4*)(rowp);
            int4 ib = *(const int4*)(rowp + 4);
            int4 ic = *(const int4*)(rowp + 8);
            iv[0][t] = ia.x; iv[1][t] = ia.y; iv[2][t] = ia.z; iv[3][t] = ia.w;
            iv[4][t] = ib.x; iv[5][t] = ib.y; iv[6][t] = ib.z; iv[7][t] = ib.w;
            iv[8][t] = ic.x;
        } else {
            #pragma unroll
            for (int k = 0; k < KK; ++k) iv[k][t] = -1;
        }
    }

    f32x4 acc[TT][2];
    #pragma unroll
    for (int t = 0; t < TT; ++t) {
        acc[t][0] = (f32x4){0, 0, 0, 0};
        acc[t][1] = (f32x4){0, 0, 0, 0};
    }

    #pragma unroll
    for (int k = 0; k < KK; ++k) {
        bf16x8 a0[TT], a1[TT];
        #pragma unroll
        for (int t = 0; t < TT; ++t) {
            a0[t] = (bf16x8){0,0,0,0,0,0,0,0};
            a1[t] = (bf16x8){0,0,0,0,0,0,0,0};
            if (iv[k][t] >= 0) {
                const bf16x8* ab = (const bf16x8*)(buf + (size_t)iv[k][t] * NIN);
                a0[t] = ab[g];
                a1[t] = ab[4 + g];
            }
        }
        #pragma unroll
        for (int kh = 0; kh < 2; ++kh) {
            #pragma unroll
            for (int ch = 0; ch < 2; ++ch) {
                bf16x8 bb = *(const bf16x8*)(
                    wlds + (size_t)((k * 2 + kh) * 2 + ch) * 512 + lane * 8);
                #pragma unroll
                for (int t = 0; t < TT; ++t) {
                    bf16x8 a = kh ? a1[t] : a0[t];
                    acc[t][ch] = __builtin_amdgcn_mfma_f32_16x16x32_bf16(
                        a, bb, acc[t][ch], 0, 0, 0);
                }
            }
        }
    }

    // C/D: row = g*4 + reg, col = ch*16 + c16; ch innermost (adjacent halves).
    float bb0 = bias[c16];
    float bb1 = bias[16 + c16];
    #pragma unroll
    for (int t = 0; t < TT; ++t) {
        #pragma unroll
        for (int reg = 0; reg < 4; ++reg) {
            int orow = r0 + t * 16 + g * 4 + reg;
            if (orow < num_out) {
                out[(size_t)orow * NOUT + c16]      = fmaxf(acc[t][0][reg] + bb0, 0.0f);
                out[(size_t)orow * NOUT + 16 + c16] = fmaxf(acc[t][1][reg] + bb1, 0.0f);
            }
        }
    }
}

// ---------------------------------------------------------------------------
// Fallback path (round-4 atomic scatter) if d_ws is too small.
__global__ void mink_prep_w32(const float* __restrict__ w,
                              unsigned short* __restrict__ wf) {
    int t = blockIdx.x * 256 + threadIdx.x;
    if (t >= KK * 4 * 64) return;
    int l = t & 63, ks = (t >> 6) & 3, k = t >> 8;
    int col = l & 31;
    int kb = ks * 16 + (l >> 5) * 4;
    #pragma unroll
    for (int j = 0; j < 8; ++j) {
        int c = kb + (j & 3) + 8 * (j >> 2);
        float v = w[(k * NIN + c) * NOUT + col];
        unsigned short hi = f2bf_rne(v);
        unsigned short lo = f2bf_rne(v - bf2f(hi));
        wf[(size_t)((k * 4 + ks) * 64 + l) * 8 + j] = hi;
        wf[(size_t)(KK * 4 * 64 * 8) + (size_t)((k * 4 + ks) * 64 + l) * 8 + j] = lo;
    }
}

__global__ void mink_init_bias(float4* __restrict__ out,
                               const float4* __restrict__ bias, int n4) {
    int i = blockIdx.x * blockDim.x + threadIdx.x;
    if (i < n4) out[i] = bias[i & 7];
}

__global__ __launch_bounds__(256) void mink_scatter_mfma(
    const float* __restrict__ feats,
    const unsigned short* __restrict__ wf,
    const int* __restrict__ out_idx,
    float* __restrict__ out,
    int ntiles) {
    int wid  = (blockIdx.x * 256 + threadIdx.x) >> 6;
    int lane = threadIdx.x & 63;
    if (wid >= ntiles) return;
    int n0   = wid * 32;
    int half = lane >> 5;
    int col  = lane & 31;

    const float* xrow = feats + (size_t)(n0 + col) * NIN;
    int kbase = half * 4;
    bf16x8 ahi[4], alo[4];
    #pragma unroll
    for (int ks = 0; ks < 4; ++ks) {
        float4 v0 = *(const float4*)(xrow + ks * 16 + kbase);
        float4 v1 = *(const float4*)(xrow + ks * 16 + kbase + 8);
        float xs[8] = {v0.x, v0.y, v0.z, v0.w, v1.x, v1.y, v1.z, v1.w};
        #pragma unroll
        for (int j = 0; j < 8; ++j) {
            unsigned short h = f2bf_rne(xs[j]);
            ahi[ks][j] = (short)h;
            alo[ks][j] = (short)f2bf_rne(xs[j] - bf2f(h));
        }
    }
    const bf16x8* wfh = (const bf16x8*)wf;
    const bf16x8* wfl = wfh + KK * 4 * 64;
    #pragma unroll 1
    for (int k = 0; k < KK; ++k) {
        f32x16 acc = {0,0,0,0,0,0,0,0,0,0,0,0,0,0,0,0};
        #pragma unroll
        for (int ks = 0; ks < 4; ++ks) {
            bf16x8 bh = wfh[(k * 4 + ks) * 64 + lane];
            bf16x8 bl = wfl[(k * 4 + ks) * 64 + lane];
            acc = __builtin_amdgcn_mfma_f32_32x32x16_bf16(ahi[ks], bh, acc, 0, 0, 0);
            acc = __builtin_amdgcn_mfma_f32_32x32x16_bf16(ahi[ks], bl, acc, 0, 0, 0);
            acc = __builtin_amdgcn_mfma_f32_32x32x16_bf16(alo[ks], bh, acc, 0, 0, 0);
        }
        #pragma unroll
        for (int rr = 0; rr < 16; ++rr) {
            int site = (rr & 3) + 8 * (rr >> 2) + 4 * half;
            int row = out_idx[(size_t)(n0 + site) * KK + k];
            unsafeAtomicAdd(out + (size_t)row * NOUT + col, acc[rr]);
        }
    }
}

__global__ void mink_relu(float4* __restrict__ out, int n4) {
    int i = blockIdx.x * blockDim.x + threadIdx.x;
    if (i < n4) {
        float4 v = out[i];
        v.x = fmaxf(v.x, 0.0f);
        v.y = fmaxf(v.y, 0.0f);
        v.z = fmaxf(v.z, 0.0f);
        v.w = fmaxf(v.w, 0.0f);
        out[i] = v;
    }
}

extern "C" void kernel_launch(void* const* d_in, const int* in_sizes, int n_in,
                              void* d_out, int out_size, void* d_ws, size_t ws_size,
                              hipStream_t stream) {
    const float* feats  = (const float*)d_in[0];  // [N, 64] f32
    const float* weight = (const float*)d_in[1];  // [9, 64, 32] f32
    const float* bias   = (const float*)d_in[2];  // [32] f32
    const int*   oidx   = (const int*)d_in[3];    // [N, 9] i32
    float* out = (float*)d_out;                   // [num_out, 32] f32

    int n       = in_sizes[0] / NIN;              // 262144
    int n4      = out_size / 4;
    int num_out = out_size / NOUT;

    // d_ws layout: wf(73728 reserved) | repmin | rep_of[n] | inv_t | buf
    unsigned short* wf = (unsigned short*)d_ws;
    size_t off = 73728;
    int* repmin = (int*)((char*)d_ws + off);  off += (size_t)num_out * 4 + 16;
    off = (off + 255) & ~(size_t)255;
    int* rep_of = (int*)((char*)d_ws + off);  off += (size_t)n * 4;
    off = (off + 255) & ~(size_t)255;
    int* inv_t  = (int*)((char*)d_ws + off);  off += (size_t)IST * num_out * 4 + 16;
    off = (off + 255) & ~(size_t)255;
    float* buf  = (float*)((char*)d_ws + off); off += (size_t)n * NIN * 4;

    if (off <= ws_size) {
        // ---- inverse-map 16x16 gather path (no output atomics)
        long long invt4c = ((long long)IST * num_out + 3) / 4;
        long long rep4c  = ((long long)num_out + 3) / 4;
        mink_setup<<<2048, 256, 0, stream>>>(
            weight, wf, (int4*)inv_t, invt4c, (int4*)repmin, rep4c);

        mink_rep<<<(n + 255) / 256, 256, 0, stream>>>(oidx, repmin, n);
        mink_resolve<<<(n + 255) / 256, 256, 0, stream>>>(oidx, repmin, rep_of, n);

        long long nthr = (long long)n * (NIN / 4) + num_out;
        mink_copy_inv<<<(int)((nthr + 255) / 256), 256, 0, stream>>>(
            (const float4*)feats, oidx, repmin, rep_of,
            (float4*)buf, inv_t, n, num_out);

        mink_dup_accum<<<(int)(((long long)n * NIN) / 256), 256, 0, stream>>>(
            feats, rep_of, buf, n);

        mink_pack16<<<(n + 255) / 256, 256, 0, stream>>>(rep_of, buf, n);

        int nwave = (num_out + 16 * TT - 1) / (16 * TT);
        mink_gather16<<<(nwave + 3) / 4, 256, 0, stream>>>(
            buf, wf, inv_t, bias, out, num_out);
    } else {
        // ---- fallback: round-4 atomic scatter
        mink_prep_w32<<<(KK * 4 * 64 + 255) / 256, 256, 0, stream>>>(weight, wf);
        mink_init_bias<<<(n4 + 255) / 256, 256, 0, stream>>>(
            (float4*)out, (const float4*)bias, n4);
        int ntiles = n / 32;
        mink_scatter_mfma<<<ntiles * 64 / 256, 256, 0, stream>>>(
            feats, wf, oidx, out, ntiles);
        mink_relu<<<(n4 + 255) / 256, 256, 0, stream>>>((float4*)out, n4);
    }
}